// Round 2
// baseline (267.714 us; speedup 1.0000x reference)
//
#include <hip/hip_runtime.h>

#define ROWLEN 4096
#define TPB    256
#define PER    16            // ROWLEN / TPB floats per thread
#define NTARGET 64.0f
#define LOG2E  1.44269504088896340736f

#if __has_builtin(__builtin_amdgcn_exp2f)
__device__ __forceinline__ float exp2_fast(float x) { return __builtin_amdgcn_exp2f(x); }
#else
__device__ __forceinline__ float exp2_fast(float x) {
    float r; asm("v_exp_f32 %0, %1" : "=v"(r) : "v"(x)); return r;
}
#endif

#if __has_builtin(__builtin_amdgcn_rcpf)
__device__ __forceinline__ float rcp_fast(float x) { return __builtin_amdgcn_rcpf(x); }
#else
__device__ __forceinline__ float rcp_fast(float x) {
    float r; asm("v_rcp_f32 %0, %1" : "=v"(r) : "v"(x)); return r;
}
#endif

// sigmoid(z) = 1/(1+e^-z) = 1/(1+2^(-z*log2e))
// caller passes tnu = -LOG2E*nu so per-element cost is fma + exp + add + rcp
__device__ __forceinline__ float sig_from(float v, float tnu) {
    float e = exp2_fast(fmaf(v, -LOG2E, tnu));
    return rcp_fast(1.0f + e);
}

__global__ __launch_bounds__(TPB) void lml_kernel(const float* __restrict__ x,
                                                  float* __restrict__ out) {
    const int t = threadIdx.x;
    const size_t base = (size_t)blockIdx.x * ROWLEN;

    // ---- load row into registers (coalesced float4) ----
    float v[PER];
#pragma unroll
    for (int k = 0; k < 4; ++k) {
        float4 f = reinterpret_cast<const float4*>(x + base)[t + k * TPB];
        v[4*k+0] = f.x; v[4*k+1] = f.y; v[4*k+2] = f.z; v[4*k+3] = f.w;
    }

    __shared__ float lds[8];
    const int wave = t >> 6;

    // ---- row max / min -> guaranteed bracket ----
    float mx = v[0], mn = v[0];
#pragma unroll
    for (int i = 1; i < PER; ++i) { mx = fmaxf(mx, v[i]); mn = fminf(mn, v[i]); }
#pragma unroll
    for (int off = 32; off >= 1; off >>= 1) {
        mx = fmaxf(mx, __shfl_xor(mx, off, 64));
        mn = fminf(mn, __shfl_xor(mn, off, 64));
    }
    if ((t & 63) == 0) { lds[wave] = mx; lds[4 + wave] = mn; }
    __syncthreads();
    mx = fmaxf(fmaxf(lds[0], lds[1]), fmaxf(lds[2], lds[3]));
    mn = fminf(fminf(lds[4], lds[5]), fminf(lds[6], lds[7]));
    __syncthreads();

    float lo = -mx - 7.0f;   // f(lo) <= 4096*sigmoid(-7) - 64 < 0
    float hi = -mn;          // f(hi) >= 4096*0.5 - 64 > 0
    float nu;

    // ---- 10 bisection sweeps ----
#pragma unroll 1
    for (int it = 0; it < 10; ++it) {
        nu = 0.5f * (lo + hi);
        const float tnu = -LOG2E * nu;
        float s = 0.0f;
#pragma unroll
        for (int i = 0; i < PER; ++i) s += sig_from(v[i], tnu);
#pragma unroll
        for (int off = 32; off >= 1; off >>= 1) s += __shfl_xor(s, off, 64);
        if ((t & 63) == 0) lds[wave] = s;
        __syncthreads();
        const float fs = (lds[0] + lds[1]) + (lds[2] + lds[3]) - NTARGET;
        __syncthreads();
        if (fs < 0.0f) lo = nu; else hi = nu;
    }

    // ---- 3 safeguarded Newton sweeps ----
    nu = 0.5f * (lo + hi);
#pragma unroll 1
    for (int it = 0; it < 3; ++it) {
        const float tnu = -LOG2E * nu;
        float s = 0.0f, w = 0.0f;
#pragma unroll
        for (int i = 0; i < PER; ++i) {
            const float si = sig_from(v[i], tnu);
            s += si;
            w = fmaf(si, -si, w + si);   // w += si*(1-si)
        }
#pragma unroll
        for (int off = 32; off >= 1; off >>= 1) {
            s += __shfl_xor(s, off, 64);
            w += __shfl_xor(w, off, 64);
        }
        if ((t & 63) == 0) { lds[wave] = s; lds[4 + wave] = w; }
        __syncthreads();
        const float fs = (lds[0] + lds[1]) + (lds[2] + lds[3]) - NTARGET;
        const float fw = (lds[4] + lds[5]) + (lds[6] + lds[7]);
        __syncthreads();
        if (fs < 0.0f) lo = nu; else hi = nu;          // keep valid bracket
        float nun = nu - fs / fmaxf(fw, 1e-12f);
        if (!(nun > lo && nun < hi)) nun = 0.5f * (lo + hi);  // safeguard
        nu = nun;
    }

    // ---- final output sweep (coalesced float4 store) ----
    const float tnu = -LOG2E * nu;
#pragma unroll
    for (int k = 0; k < 4; ++k) {
        float4 f;
        f.x = sig_from(v[4*k+0], tnu);
        f.y = sig_from(v[4*k+1], tnu);
        f.z = sig_from(v[4*k+2], tnu);
        f.w = sig_from(v[4*k+3], tnu);
        reinterpret_cast<float4*>(out + base)[t + k * TPB] = f;
    }
}

extern "C" void kernel_launch(void* const* d_in, const int* in_sizes, int n_in,
                              void* d_out, int out_size, void* d_ws, size_t ws_size,
                              hipStream_t stream) {
    const float* x = (const float*)d_in[0];
    float* out = (float*)d_out;
    const int rows = in_sizes[0] / ROWLEN;   // 8192
    lml_kernel<<<rows, TPB, 0, stream>>>(x, out);
}

// Round 3
// 227.731 us; speedup vs baseline: 1.1756x; 1.1756x over previous
//
#include <hip/hip_runtime.h>

#define ROWLEN 4096
#define TPB    256
#define PER    16            // ROWLEN / TPB floats per thread
#define NTARGET 64.0f
#define LOG2E  1.44269504088896340736f

__device__ __forceinline__ float exp2_fast(float x) {
    float r; asm("v_exp_f32 %0, %1" : "=v"(r) : "v"(x)); return r;
}
__device__ __forceinline__ float rcp_fast(float x) {
    float r; asm("v_rcp_f32 %0, %1" : "=v"(r) : "v"(x)); return r;
}
__device__ __forceinline__ float log2_fast(float x) {
    float r; asm("v_log_f32 %0, %1" : "=v"(r) : "v"(x)); return r;
}

// sigmoid(z) = 1/(1+e^-z) = 1/(1+2^(-z*log2e)); caller passes tnu = -LOG2E*nu
__device__ __forceinline__ float sig_from(float v, float tnu) {
    float e = exp2_fast(fmaf(v, -LOG2E, tnu));
    return rcp_fast(1.0f + e);
}

__global__ __launch_bounds__(TPB) void lml_kernel(const float* __restrict__ x,
                                                  float* __restrict__ out) {
    const int t = threadIdx.x;
    const size_t base = (size_t)blockIdx.x * ROWLEN;

    // ---- sweep A: load row into registers; exp-sum + row min ----
    float v[PER];
#pragma unroll
    for (int k = 0; k < 4; ++k) {
        float4 f = reinterpret_cast<const float4*>(x + base)[t + k * TPB];
        v[4*k+0] = f.x; v[4*k+1] = f.y; v[4*k+2] = f.z; v[4*k+3] = f.w;
    }

    float S = 0.0f, mn = v[0];
#pragma unroll
    for (int i = 0; i < PER; ++i) {
        S += exp2_fast(v[i] * LOG2E);
        mn = fminf(mn, v[i]);
    }

    __shared__ float lds[8];
    const int wave = t >> 6;
#pragma unroll
    for (int off = 32; off >= 1; off >>= 1) {
        S += __shfl_xor(S, off, 64);
        mn = fminf(mn, __shfl_xor(mn, off, 64));
    }
    if ((t & 63) == 0) { lds[wave] = S; lds[4 + wave] = mn; }
    __syncthreads();
    S  = (lds[0] + lds[1]) + (lds[2] + lds[3]);
    mn = fminf(fminf(lds[4], lds[5]), fminf(lds[6], lds[7]));
    __syncthreads();

    // exp-model warm start: nu0 = ln64 - lnS = (6 - log2 S)/log2 e.
    // sigma(z) <= e^z  =>  f(nu0) <= 64  =>  nu0 is a guaranteed LOWER bracket.
    float nu = (6.0f - log2_fast(S)) * (1.0f / LOG2E);
    float lo = nu;
    float hi = -mn;          // all sigma >= 0.5 => sum >= 2048 > 64

    // ---- 3 safeguarded log-space Newton sweeps ----
#pragma unroll 1
    for (int it = 0; it < 3; ++it) {
        const float tnu = -LOG2E * nu;
        float s = 0.0f, w = 0.0f;
#pragma unroll
        for (int i = 0; i < PER; ++i) {
            const float si = sig_from(v[i], tnu);
            s += si;
            w = fmaf(si, -si, w + si);   // w += si*(1-si)
        }
#pragma unroll
        for (int off = 32; off >= 1; off >>= 1) {
            s += __shfl_xor(s, off, 64);
            w += __shfl_xor(w, off, 64);
        }
        if ((t & 63) == 0) { lds[wave] = s; lds[4 + wave] = w; }
        __syncthreads();
        const float fs = (lds[0] + lds[1]) + (lds[2] + lds[3]);
        const float fw = (lds[4] + lds[5]) + (lds[6] + lds[7]);
        __syncthreads();
        if (fs < NTARGET) lo = nu; else hi = nu;   // keep valid bracket
        // log-space Newton: h = ln(fs/64); nu -= h * fs / fw
        const float h = (log2_fast(fs) - 6.0f) * (1.0f / LOG2E);
        float nun = nu - h * fs * rcp_fast(fmaxf(fw, 1e-20f));
        if (!(nun > lo && nun < hi)) nun = 0.5f * (lo + hi);  // safeguard
        nu = nun;
    }

    // ---- final output sweep (coalesced float4 store) ----
    const float tnu = -LOG2E * nu;
#pragma unroll
    for (int k = 0; k < 4; ++k) {
        float4 f;
        f.x = sig_from(v[4*k+0], tnu);
        f.y = sig_from(v[4*k+1], tnu);
        f.z = sig_from(v[4*k+2], tnu);
        f.w = sig_from(v[4*k+3], tnu);
        reinterpret_cast<float4*>(out + base)[t + k * TPB] = f;
    }
}

extern "C" void kernel_launch(void* const* d_in, const int* in_sizes, int n_in,
                              void* d_out, int out_size, void* d_ws, size_t ws_size,
                              hipStream_t stream) {
    const float* x = (const float*)d_in[0];
    float* out = (float*)d_out;
    const int rows = in_sizes[0] / ROWLEN;   // 8192
    lml_kernel<<<rows, TPB, 0, stream>>>(x, out);
}